// Round 7
// baseline (684.653 us; speedup 1.0000x reference)
//
#include <hip/hip_runtime.h>
#include <hip/hip_bf16.h>

// ---------------------------------------------------------------------------
// LinearMoLoraLayer: out = x@W_base^T + b_base + 2.0 * sum_e route[e]*(x@A_e^T)@B_e^T
// Shapes: x[8192][4096] f32, W_base[4096][4096], W_gate[8][4096],
//         A[8][16][4096], B[8][4096][16], out[8192][4096] f32.
// Strategy: bf16 MFMA everywhere (threshold permits), LoRA-up fused into the
// main GEMM K-loop as 4 extra K-steps (Kcat = 4096 + 128 = 132*32).
// ---------------------------------------------------------------------------

typedef __attribute__((ext_vector_type(8))) short  bf16x8;
typedef __attribute__((ext_vector_type(4))) float  f32x4;
typedef __attribute__((ext_vector_type(4))) unsigned short us4;
typedef __attribute__((ext_vector_type(4))) float  fl4;

// f32 -> bf16 round-to-nearest-even (inputs are finite normals)
__device__ __forceinline__ unsigned short f2bf(float f) {
  unsigned int u = __float_as_uint(f);
  u += 0x7FFFu + ((u >> 16) & 1u);
  return (unsigned short)(u >> 16);
}

// async global->LDS, 16B per lane; LDS dest is wave-uniform base + lane*16
__device__ __forceinline__ void gload16(const void* g, void* l) {
  __builtin_amdgcn_global_load_lds(
      (const __attribute__((address_space(1))) unsigned int*)g,
      (__attribute__((address_space(3))) unsigned int*)l, 16, 0, 0);
}

// ---- workspace layout (bytes) ---------------------------------------------
#define WS_XBF 0u           // [8192][4096] bf16  = 67108864
#define WS_WBF 67108864u    // [4096][4096] bf16  = 33554432
#define WS_AG  100663296u   // [144][4096]  bf16  = 1179648 (rows 0..7 W_gate, 8..135 A, 136..143 zero)
#define WS_U   101842944u   // [4096][128]  bf16  = 1048576 (U[o][e*16+r] = 2*B[e][o][r])
#define WS_HW  102891520u   // [8192][128]  bf16  = 2097152 (hw = h*route)

// ---------------------------------------------------------------------------
// Kernel 1: all conversions/packing in one grid-stride pass (float4 units)
// ---------------------------------------------------------------------------
__global__ __launch_bounds__(256) void prep_kernel(
    const float* __restrict__ x, const float* __restrict__ Wb,
    const float* __restrict__ Wg, const float* __restrict__ A,
    const float* __restrict__ B,
    unsigned short* __restrict__ Xbf, unsigned short* __restrict__ Wbf,
    unsigned short* __restrict__ AG, unsigned short* __restrict__ U)
{
  const long N0 = 8388608;          // x           (33554432/4)
  const long N1 = N0 + 4194304;     // W_base
  const long N2 = N1 + 139264;      // W_gate(8192) + A(131072) -> AG rows 0..135
  const long N3 = N2 + 8192;        // AG zero rows 136..143
  const long N4 = N3 + 131072;      // U pack
  long i = (long)blockIdx.x * blockDim.x + threadIdx.x;
  long stride = (long)gridDim.x * blockDim.x;
  for (; i < N4; i += stride) {
    if (i < N1) {
      const float* s; unsigned short* d; long j;
      if (i < N0) { s = x;  d = Xbf; j = i; }
      else        { s = Wb; d = Wbf; j = i - N0; }
      fl4 v = ((const fl4*)s)[j];
      us4 o; o[0]=f2bf(v[0]); o[1]=f2bf(v[1]); o[2]=f2bf(v[2]); o[3]=f2bf(v[3]);
      ((us4*)d)[j] = o;
    } else if (i < N2) {
      long j = i - N1;  // us4 index into AG (W_gate then A, contiguous)
      fl4 v = (j < 8192) ? ((const fl4*)Wg)[j] : ((const fl4*)A)[j - 8192];
      us4 o; o[0]=f2bf(v[0]); o[1]=f2bf(v[1]); o[2]=f2bf(v[2]); o[3]=f2bf(v[3]);
      ((us4*)AG)[j] = o;
    } else if (i < N3) {
      long j = i - N2;
      us4 z = (us4)0;
      ((us4*)(AG + 136*4096))[j] = z;
    } else {
      long j = i - N3;              // us4 index into U [4096][128]
      long o = j >> 5;              // 0..4095 (d_out row)
      long c4 = j & 31;             // (e*16+r)/4
      long e = c4 >> 2, r4 = c4 & 3;
      fl4 v = ((const fl4*)B)[e*16384 + o*4 + r4];
      us4 t; t[0]=f2bf(2.f*v[0]); t[1]=f2bf(2.f*v[1]);
             t[2]=f2bf(2.f*v[2]); t[3]=f2bf(2.f*v[3]);
      ((us4*)U)[j] = t;
    }
  }
}

// ---------------------------------------------------------------------------
// Kernel 2: gating logits + low-rank h in one MFMA pass; softmax; hw -> bf16
// Block: 256 thr (4 waves), BM=64 rows, N=144 (8 gate + 128 h + 8 pad), K=4096
// ---------------------------------------------------------------------------
__global__ __launch_bounds__(256) void gate_h_kernel(
    const unsigned short* __restrict__ Xbf,
    const unsigned short* __restrict__ AG,
    unsigned short* __restrict__ HW)
{
  __shared__ unsigned short Xt[64*32];      // [64][32]
  __shared__ unsigned short At[144*32];     // [144][32]
  __shared__ float accs[64*136];            // logits(8) + h(128) per row

  int tid = threadIdx.x;
  int lane = tid & 63;
  int w = tid >> 6;
  long brow = (long)blockIdx.x * 64;

  f32x4 acc[9];
#pragma unroll
  for (int i = 0; i < 9; ++i) acc[i] = (f32x4){0.f,0.f,0.f,0.f};

  int lrow = lane >> 2;          // 0..15
  int lcol = (lane & 3) * 8;     // 0,8,16,24

  for (int kb = 0; kb < 128; ++kb) {
    __syncthreads();
    // stage X tile: wave w covers rows w*16..+16
    gload16(Xbf + (brow + w*16 + lrow)*4096 + kb*32 + lcol, (char*)Xt + w*1024);
    // stage AG tile: 9 chunks of 16 rows
    for (int c = w; c < 9; c += 4)
      gload16(AG + (long)(c*16 + lrow)*4096 + kb*32 + lcol, (char*)At + c*1024);
    __syncthreads();
    int r16 = lane & 15, kh = lane >> 4;
    bf16x8 a = *(const bf16x8*)&Xt[(w*16 + r16)*32 + kh*8];
#pragma unroll
    for (int n = 0; n < 9; ++n) {
      bf16x8 b = *(const bf16x8*)&At[(n*16 + r16)*32 + kh*8];
      acc[n] = __builtin_amdgcn_mfma_f32_16x16x32_bf16(a, b, acc[n], 0, 0, 0);
    }
  }
  __syncthreads();
  {
    int r16 = lane & 15, rg = lane >> 4;
#pragma unroll
    for (int n = 0; n < 9; ++n) {
      int col = n*16 + r16;
      if (col < 136) {
#pragma unroll
        for (int j = 0; j < 4; ++j)
          accs[(w*16 + rg*4 + j)*136 + col] = acc[n][j];
      }
    }
  }
  __syncthreads();
  {
    int r = tid >> 2;            // 0..63
    int q = tid & 3;             // quarter of the 128 h-cols
    const float* rp = &accs[r*136];
    float mx = rp[0];
#pragma unroll
    for (int e = 1; e < 8; ++e) mx = fmaxf(mx, rp[e]);
    float ex[8]; float s = 0.f;
#pragma unroll
    for (int e = 0; e < 8; ++e) { ex[e] = __expf(rp[e] - mx); s += ex[e]; }
    float inv = 1.f / s;
#pragma unroll
    for (int jj = 0; jj < 8; ++jj) {
      int col = q*32 + jj*4;
      float rt = ex[col >> 4] * inv;   // same expert for 4 consecutive cols
      us4 o;
      o[0] = f2bf(rp[8+col+0] * rt);
      o[1] = f2bf(rp[8+col+1] * rt);
      o[2] = f2bf(rp[8+col+2] * rt);
      o[3] = f2bf(rp[8+col+3] * rt);
      *(us4*)&HW[(brow + r)*128 + col] = o;
    }
  }
}

// ---------------------------------------------------------------------------
// Kernel 3: main GEMM, m97 structure. 128x128 tile, 4 waves (2x2), each wave
// 64x64 = 4x4 fragments of 16x16x32 bf16. K-loop: 128 steps over (Xbf,Wbf)
// then 4 steps over (HW,U) — the fused LoRA-up. Bias in epilogue, f32 out.
// ---------------------------------------------------------------------------
__global__ __launch_bounds__(256) void gemm_main(
    const unsigned short* __restrict__ Xbf,
    const unsigned short* __restrict__ Wbf,
    const unsigned short* __restrict__ HW,
    const unsigned short* __restrict__ U,
    const float* __restrict__ bias,
    float* __restrict__ out)
{
  __shared__ unsigned short At[128*32];
  __shared__ unsigned short Bt[128*32];

  int tid = threadIdx.x;
  int lane = tid & 63;
  int w = tid >> 6;
  int wr = w >> 1, wc = w & 1;

  int bid = blockIdx.x;        // 2048 = 64 M-tiles x 32 N-tiles, bn fastest
  long brow = (long)(bid >> 5) * 128;
  long bcol = (long)(bid & 31) * 128;

  f32x4 acc[4][4];
#pragma unroll
  for (int m = 0; m < 4; ++m)
#pragma unroll
    for (int n = 0; n < 4; ++n) acc[m][n] = (f32x4){0.f,0.f,0.f,0.f};

  int lrow = lane >> 2;          // 0..15
  int lcol = (lane & 3) * 8;     // 0,8,16,24
  int r16 = lane & 15, kh = lane >> 4;

  auto step = [&](const unsigned short* __restrict__ pA, long ldA,
                  const unsigned short* __restrict__ pB, long ldB, int k0) {
    __syncthreads();
#pragma unroll
    for (int i = 0; i < 2; ++i) {
      int chunk = w*2 + i;               // 0..7, 16 rows each
      int row = chunk*16 + lrow;
      gload16(pA + (brow + row)*ldA + k0 + lcol, (char*)At + chunk*1024);
      gload16(pB + (bcol + row)*ldB + k0 + lcol, (char*)Bt + chunk*1024);
    }
    __syncthreads();
    bf16x8 af[4], bfr[4];
#pragma unroll
    for (int m = 0; m < 4; ++m)
      af[m] = *(const bf16x8*)&At[(wr*64 + m*16 + r16)*32 + kh*8];
#pragma unroll
    for (int n = 0; n < 4; ++n)
      bfr[n] = *(const bf16x8*)&Bt[(wc*64 + n*16 + r16)*32 + kh*8];
#pragma unroll
    for (int m = 0; m < 4; ++m)
#pragma unroll
      for (int n = 0; n < 4; ++n)
        acc[m][n] = __builtin_amdgcn_mfma_f32_16x16x32_bf16(af[m], bfr[n], acc[m][n], 0, 0, 0);
  };

  for (int kb = 0; kb < 128; ++kb) step(Xbf, 4096, Wbf, 4096, kb*32);
  for (int kb = 0; kb < 4;   ++kb) step(HW, 128, U, 128, kb*32);

  // epilogue: C/D layout col=lane&15, row=(lane>>4)*4+reg (m89/m91-verified)
  int rg = lane >> 4;
#pragma unroll
  for (int n = 0; n < 4; ++n) {
    long col = bcol + wc*64 + n*16 + r16;
    float b = bias[col];
#pragma unroll
    for (int m = 0; m < 4; ++m) {
      long row0 = brow + wr*64 + m*16 + rg*4;
#pragma unroll
      for (int j = 0; j < 4; ++j)
        out[(row0 + j)*4096 + col] = acc[m][n][j] + b;
    }
  }
}

// ---------------------------------------------------------------------------
extern "C" void kernel_launch(void* const* d_in, const int* in_sizes, int n_in,
                              void* d_out, int out_size, void* d_ws, size_t ws_size,
                              hipStream_t stream) {
  (void)in_sizes; (void)n_in; (void)out_size; (void)ws_size;
  const float* x  = (const float*)d_in[0];
  const float* Wb = (const float*)d_in[1];
  const float* bb = (const float*)d_in[2];
  const float* Wg = (const float*)d_in[3];
  const float* A  = (const float*)d_in[4];
  const float* B  = (const float*)d_in[5];
  float* out = (float*)d_out;
  char* ws = (char*)d_ws;

  unsigned short* Xbf = (unsigned short*)(ws + WS_XBF);
  unsigned short* Wbf = (unsigned short*)(ws + WS_WBF);
  unsigned short* AG  = (unsigned short*)(ws + WS_AG);
  unsigned short* U   = (unsigned short*)(ws + WS_U);
  unsigned short* HW  = (unsigned short*)(ws + WS_HW);

  hipLaunchKernelGGL(prep_kernel, dim3(2048), dim3(256), 0, stream,
                     x, Wb, Wg, A, B, Xbf, Wbf, AG, U);
  hipLaunchKernelGGL(gate_h_kernel, dim3(128), dim3(256), 0, stream,
                     Xbf, AG, HW);
  hipLaunchKernelGGL(gemm_main, dim3(2048), dim3(256), 0, stream,
                     Xbf, Wbf, HW, U, bb, out);
}

// Round 8
// 564.208 us; speedup vs baseline: 1.2135x; 1.2135x over previous
//
#include <hip/hip_runtime.h>
#include <hip/hip_bf16.h>

// ---------------------------------------------------------------------------
// LinearMoLoraLayer: out = x@W_base^T + b_base + 2.0 * sum_e route[e]*(x@A_e^T)@B_e^T
// x[8192][4096] f32, W_base[4096][4096], W_gate[8][4096], A[8][16][4096],
// B[8][4096][16], out[8192][4096] f32.
// R8: gemm -> 256x256 8-phase template (T2 swizzle + T3/T4 counted vmcnt + T5
// setprio); gate_h -> split-K x2, BM=32 (512 blocks) + reduce kernel.
// ---------------------------------------------------------------------------

typedef __attribute__((ext_vector_type(8))) short  bf16x8;
typedef __attribute__((ext_vector_type(4))) float  f32x4;
typedef __attribute__((ext_vector_type(4))) unsigned short us4;
typedef __attribute__((ext_vector_type(4))) float  fl4;

__device__ __forceinline__ unsigned short f2bf(float f) {
  unsigned int u = __float_as_uint(f);
  u += 0x7FFFu + ((u >> 16) & 1u);
  return (unsigned short)(u >> 16);
}
__device__ __forceinline__ float bf2f(unsigned short u) {
  return __uint_as_float(((unsigned int)u) << 16);
}
__device__ __forceinline__ void gload16(const void* g, void* l) {
  __builtin_amdgcn_global_load_lds(
      (const __attribute__((address_space(1))) unsigned int*)g,
      (__attribute__((address_space(3))) unsigned int*)l, 16, 0, 0);
}

#define BAR() do { asm volatile("" ::: "memory"); \
                   __builtin_amdgcn_s_barrier();  \
                   asm volatile("" ::: "memory"); } while (0)
#define VMCNT6() asm volatile("s_waitcnt vmcnt(6)" ::: "memory")
#define VMCNT0() asm volatile("s_waitcnt vmcnt(0)" ::: "memory")

// ---- workspace layout (bytes) ---------------------------------------------
#define WS_XBF 0u           // [8192][4096] bf16
#define WS_WBF 67108864u    // [4096][4096] bf16
#define WS_AG  100663296u   // [144][4096]  bf16 (rows 0..7 Wg, 8..135 A)
#define WS_U   101842944u   // [4096][128]  bf16 (U[o][e*16+r] = 2*B[e][o][r])
#define WS_HW  102891520u   // [8192][128]  bf16 (hw = h*route)
#define WS_HP  104988672u   // [2][8192][136] bf16 partial (logits8 + h128)

// ---------------------------------------------------------------------------
// Kernel 1: conversions/packing (unchanged from verified baseline)
// ---------------------------------------------------------------------------
__global__ __launch_bounds__(256) void prep_kernel(
    const float* __restrict__ x, const float* __restrict__ Wb,
    const float* __restrict__ Wg, const float* __restrict__ A,
    const float* __restrict__ B,
    unsigned short* __restrict__ Xbf, unsigned short* __restrict__ Wbf,
    unsigned short* __restrict__ AG, unsigned short* __restrict__ U)
{
  const long N0 = 8388608;
  const long N1 = N0 + 4194304;
  const long N2 = N1 + 139264;
  const long N3 = N2 + 8192;
  const long N4 = N3 + 131072;
  long i = (long)blockIdx.x * blockDim.x + threadIdx.x;
  long stride = (long)gridDim.x * blockDim.x;
  for (; i < N4; i += stride) {
    if (i < N1) {
      const float* s; unsigned short* d; long j;
      if (i < N0) { s = x;  d = Xbf; j = i; }
      else        { s = Wb; d = Wbf; j = i - N0; }
      fl4 v = ((const fl4*)s)[j];
      us4 o; o[0]=f2bf(v[0]); o[1]=f2bf(v[1]); o[2]=f2bf(v[2]); o[3]=f2bf(v[3]);
      ((us4*)d)[j] = o;
    } else if (i < N2) {
      long j = i - N1;
      fl4 v = (j < 8192) ? ((const fl4*)Wg)[j] : ((const fl4*)A)[j - 8192];
      us4 o; o[0]=f2bf(v[0]); o[1]=f2bf(v[1]); o[2]=f2bf(v[2]); o[3]=f2bf(v[3]);
      ((us4*)AG)[j] = o;
    } else if (i < N3) {
      long j = i - N2;
      us4 z = (us4)0;
      ((us4*)(AG + 136*4096))[j] = z;
    } else {
      long j = i - N3;
      long o = j >> 5;
      long c4 = j & 31;
      long e = c4 >> 2, r4 = c4 & 3;
      fl4 v = ((const fl4*)B)[e*16384 + o*4 + r4];
      us4 t; t[0]=f2bf(2.f*v[0]); t[1]=f2bf(2.f*v[1]);
             t[2]=f2bf(2.f*v[2]); t[3]=f2bf(2.f*v[3]);
      ((us4*)U)[j] = t;
    }
  }
}

// ---------------------------------------------------------------------------
// Kernel 2a: gate/h partial GEMM. grid 512 = 256 M-tiles(BM=32) x 2 K-halves.
// Block: 256 thr (4 waves: wm=w&1 M-half, wn=w>>1 N-half). Writes bf16
// partial sums HP[ks][8192][136] (cols 0..7 logits, 8..135 h).
// ---------------------------------------------------------------------------
__global__ __launch_bounds__(256) void gate_partial(
    const unsigned short* __restrict__ Xbf,
    const unsigned short* __restrict__ AG,
    unsigned short* __restrict__ HP)
{
  __shared__ unsigned short Xt[32*32];
  __shared__ unsigned short At[160*32];   // rows 144..159 never staged/used

  int tid = threadIdx.x;
  int lane = tid & 63;
  int w = tid >> 6;
  int wm = w & 1, wn = w >> 1;
  int mt = blockIdx.x >> 1, ks = blockIdx.x & 1;
  long brow = (long)mt * 32;
  long kbase = (long)ks * 2048;

  f32x4 acc[5];
#pragma unroll
  for (int i = 0; i < 5; ++i) acc[i] = (f32x4){0.f,0.f,0.f,0.f};

  int r16 = lane & 15, kh = lane >> 4;

  for (int kb = 0; kb < 64; ++kb) {
    long kc = kbase + kb*32;
    __syncthreads();
    for (int s = w; s < 11; s += 4) {
      if (s < 2)
        gload16(Xbf + (brow + s*16 + (lane>>2))*4096 + kc + (lane&3)*8,
                (char*)Xt + s*1024);
      else
        gload16(AG + ((long)((s-2)*16 + (lane>>2)))*4096 + kc + (lane&3)*8,
                (char*)At + (s-2)*1024);
    }
    __syncthreads();
    bf16x8 a = *(const bf16x8*)&Xt[(wm*16 + r16)*32 + kh*8];
#pragma unroll
    for (int c = 0; c < 5; ++c) {
      int ch = wn*5 + c;   // wn=0: 0..4, wn=1: 5..9 (9 = dummy)
      bf16x8 b = *(const bf16x8*)&At[(ch*16 + r16)*32 + kh*8];
      acc[c] = __builtin_amdgcn_mfma_f32_16x16x32_bf16(a, b, acc[c], 0, 0, 0);
    }
  }

  long rowg = brow + wm*16 + (lane>>4)*4;
#pragma unroll
  for (int c = 0; c < 5; ++c) {
    int ch = wn*5 + c;
    if (ch > 8) continue;
    int col = ch*16 + r16;
    if (col < 136) {
#pragma unroll
      for (int j = 0; j < 4; ++j)
        HP[((long)ks*8192 + rowg + j)*136 + col] = f2bf(acc[c][j]);
    }
  }
}

// ---------------------------------------------------------------------------
// Kernel 2b: reduce partials, softmax gate, weight h, write HW bf16.
// grid 128 x 256 thr; thread = (row = bid*64 + tid>>2, quarter q = tid&3).
// ---------------------------------------------------------------------------
__global__ __launch_bounds__(256) void gate_reduce(
    const unsigned short* __restrict__ HP,
    unsigned short* __restrict__ HW)
{
  int tid = threadIdx.x;
  long r = (long)blockIdx.x*64 + (tid>>2);
  int q = tid & 3;
  const us4* r0 = (const us4*)(HP + r*136);
  const us4* r1 = (const us4*)(HP + (8192 + r)*136);

  us4 la0 = r0[0], la1 = r0[1], lb0 = r1[0], lb1 = r1[1];
  float lg[8];
#pragma unroll
  for (int e = 0; e < 4; ++e) {
    lg[e]   = bf2f(la0[e]) + bf2f(lb0[e]);
    lg[4+e] = bf2f(la1[e]) + bf2f(lb1[e]);
  }
  float mx = lg[0];
#pragma unroll
  for (int e = 1; e < 8; ++e) mx = fmaxf(mx, lg[e]);
  float ex[8]; float s = 0.f;
#pragma unroll
  for (int e = 0; e < 8; ++e) { ex[e] = __expf(lg[e] - mx); s += ex[e]; }
  float inv = 1.f / s;

  us4* ow = (us4*)(HW + r*128);
#pragma unroll
  for (int k = 0; k < 8; ++k) {
    us4 h0 = r0[2 + q*8 + k], h1 = r1[2 + q*8 + k];
    int col0 = q*32 + k*4;
    float rt = ex[col0 >> 4] * inv;
    us4 o;
#pragma unroll
    for (int i = 0; i < 4; ++i)
      o[i] = f2bf((bf2f(h0[i]) + bf2f(h1[i])) * rt);
    ow[q*8 + k] = o;
  }
}

// ---------------------------------------------------------------------------
// Kernel 3: 256x256 8-phase GEMM (m201 template). 512 thr = 8 waves (2Mx4N),
// BK=64, 128 KiB LDS double-buffered, XOR swizzle slot^=(row&7) on staging
// source + ds_read (involution), counted vmcnt(6) once per K-tile, setprio
// around each 16-MFMA quadrant. K-loop: 64 tiles (Xbf,Wbf) + 2 tiles (HW,U).
// ---------------------------------------------------------------------------
#define NKT 66

struct Op { const unsigned short* a; const unsigned short* b; long lda, ldb, k0; };

__device__ __forceinline__ Op getop(int kt,
    const unsigned short* X, const unsigned short* W,
    const unsigned short* HW, const unsigned short* U) {
  Op o;
  if (kt < 64) { o.a = X;  o.b = W; o.lda = 4096; o.ldb = 4096; o.k0 = (long)kt*64; }
  else         { o.a = HW; o.b = U; o.lda = 128;  o.ldb = 128;  o.k0 = (long)(kt-64)*64; }
  return o;
}

// stage A-half(mh): rows [mh*64,+64) U [128+mh*64,+64), 2 gloads/thread
__device__ __forceinline__ void stA(const unsigned short* src, long ld, long k0,
                                    long brow, char* dst, int mh, int t) {
  int l = t & 63, w = t >> 6;
  int kc = ((l & 7) ^ (l >> 3)) << 3;     // pre-swizzled source chunk (elements)
#pragma unroll
  for (int i = 0; i < 2; ++i) {
    long grow = (long)i*128 + mh*64 + w*8 + (l>>3);
    gload16(src + (brow + grow)*ld + k0 + kc,
            dst + mh*8192 + i*16384 + (long)t*16);
  }
}
// stage B-half(nh): rows wcS*64 + nh*32 + [0,32) for wcS=0..3
__device__ __forceinline__ void stB(const unsigned short* src, long ld, long k0,
                                    long bcol, char* dst, int nh, int t) {
  int l = t & 63, w = t >> 6;
  int kc = ((l & 7) ^ (l >> 3)) << 3;
#pragma unroll
  for (int i = 0; i < 2; ++i) {
    long grow = ((long)i*2 + (w>>2))*64 + nh*32 + (w&3)*8 + (l>>3);
    gload16(src + (bcol + grow)*ld + k0 + kc,
            dst + i*16384 + (w>>2)*8192 + nh*4096 + ((long)(w&3)*64 + l)*16);
  }
}

__device__ __forceinline__ bf16x8 frag(const char* buf, int row, int ks, int kh, int l7) {
  int slot = (ks*4 + kh) ^ l7;            // swizzled read (matches staging)
  return *(const bf16x8*)(buf + (long)row*128 + slot*16);
}

__global__ __launch_bounds__(512, 2) void gemm8(
    const unsigned short* __restrict__ Xbf,
    const unsigned short* __restrict__ Wbf,
    const unsigned short* __restrict__ HW,
    const unsigned short* __restrict__ U,
    const float* __restrict__ bias,
    float* __restrict__ out)
{
  __shared__ char lds[131072];            // A: [buf][256][64], B at +65536

  int tid = threadIdx.x;
  int lane = tid & 63;
  int w = tid >> 6;
  int wr = w >> 2, wc = w & 3;
  int r16 = lane & 15, kh = lane >> 4, l7 = lane & 7;

  int bid = blockIdx.x;                   // 512 = 32 M x 16 N, bn fastest
  long brow = (long)(bid >> 4) * 256;
  long bcol = (long)(bid & 15) * 256;

  f32x4 acc[2][2][4][2];
#pragma unroll
  for (int mh = 0; mh < 2; ++mh)
#pragma unroll
    for (int nh = 0; nh < 2; ++nh)
#pragma unroll
      for (int m = 0; m < 4; ++m)
#pragma unroll
        for (int n = 0; n < 2; ++n) acc[mh][nh][m][n] = (f32x4){0.f,0.f,0.f,0.f};

  char* A0b = lds;                        // A buf0
  char* B0b = lds + 65536;                // B buf0

  // Prologue: tile0 all 4 halves + tile1 {A0,B0,B1}; wait to 3 halves in flight
  {
    Op o0 = getop(0, Xbf, Wbf, HW, U);
    Op o1 = getop(1, Xbf, Wbf, HW, U);
    stA(o0.a, o0.lda, o0.k0, brow, A0b, 0, tid);
    stB(o0.b, o0.ldb, o0.k0, bcol, B0b, 0, tid);
    stB(o0.b, o0.ldb, o0.k0, bcol, B0b, 1, tid);
    stA(o0.a, o0.lda, o0.k0, brow, A0b, 1, tid);
    stA(o1.a, o1.lda, o1.k0, brow, A0b + 32768, 0, tid);
    stB(o1.b, o1.ldb, o1.k0, bcol, B0b + 32768, 0, tid);
    stB(o1.b, o1.ldb, o1.k0, bcol, B0b + 32768, 1, tid);
    VMCNT6();
    BAR();
  }

  bf16x8 a[4][2], b0[2][2], b1[2][2];

  for (int kt = 0; kt < NKT; ++kt) {
    const char* rA = A0b + (kt & 1) * 32768;
    const char* rB = B0b + (kt & 1) * 32768;
    char* wA1 = A0b + ((kt + 1) & 1) * 32768;   // stage dest for kt+1
    char* wA2 = A0b + (kt & 1) * 32768;         // stage dest for kt+2
    char* wB2 = B0b + (kt & 1) * 32768;
    Op o1 = getop(kt + 1 < NKT ? kt + 1 : 0, Xbf, Wbf, HW, U);
    Op o2 = getop(kt + 2 < NKT ? kt + 2 : 0, Xbf, Wbf, HW, U);

    // ---- P1: read A(mh=0)+B(nh=0) [12 ds_reads]; stage A1(kt+1); Q(0,0)
#pragma unroll
    for (int m = 0; m < 4; ++m)
#pragma unroll
      for (int ks = 0; ks < 2; ++ks)
        a[m][ks] = frag(rA, wr*128 + m*16 + r16, ks, kh, l7);
#pragma unroll
    for (int n = 0; n < 2; ++n)
#pragma unroll
      for (int ks = 0; ks < 2; ++ks)
        b0[n][ks] = frag(rB, wc*64 + n*16 + r16, ks, kh, l7);
    if (kt + 1 < NKT) stA(o1.a, o1.lda, o1.k0, brow, wA1, 1, tid);
    BAR();
    __builtin_amdgcn_s_setprio(1);
#pragma unroll
    for (int m = 0; m < 4; ++m)
#pragma unroll
      for (int n = 0; n < 2; ++n)
#pragma unroll
        for (int ks = 0; ks < 2; ++ks)
          acc[0][0][m][n] = __builtin_amdgcn_mfma_f32_16x16x32_bf16(
              a[m][ks], b0[n][ks], acc[0][0][m][n], 0, 0, 0);
    __builtin_amdgcn_s_setprio(0);
    BAR();

    // ---- P2: read B(nh=1) [4]; stage A0(kt+2); Q(0,1)
#pragma unroll
    for (int n = 0; n < 2; ++n)
#pragma unroll
      for (int ks = 0; ks < 2; ++ks)
        b1[n][ks] = frag(rB, wc*64 + 32 + n*16 + r16, ks, kh, l7);
    if (kt + 2 < NKT) stA(o2.a, o2.lda, o2.k0, brow, wA2, 0, tid);
    BAR();
    __builtin_amdgcn_s_setprio(1);
#pragma unroll
    for (int m = 0; m < 4; ++m)
#pragma unroll
      for (int n = 0; n < 2; ++n)
#pragma unroll
        for (int ks = 0; ks < 2; ++ks)
          acc[0][1][m][n] = __builtin_amdgcn_mfma_f32_16x16x32_bf16(
              a[m][ks], b1[n][ks], acc[0][1][m][n], 0, 0, 0);
    __builtin_amdgcn_s_setprio(0);
    BAR();

    // ---- P3: read A(mh=1) [8]; stage B0(kt+2); Q(1,1)
#pragma unroll
    for (int m = 0; m < 4; ++m)
#pragma unroll
      for (int ks = 0; ks < 2; ++ks)
        a[m][ks] = frag(rA, wr*128 + 64 + m*16 + r16, ks, kh, l7);
    if (kt + 2 < NKT) stB(o2.b, o2.ldb, o2.k0, bcol, wB2, 0, tid);
    BAR();
    __builtin_amdgcn_s_setprio(1);
#pragma unroll
    for (int m = 0; m < 4; ++m)
#pragma unroll
      for (int n = 0; n < 2; ++n)
#pragma unroll
        for (int ks = 0; ks < 2; ++ks)
          acc[1][1][m][n] = __builtin_amdgcn_mfma_f32_16x16x32_bf16(
              a[m][ks], b1[n][ks], acc[1][1][m][n], 0, 0, 0);
    __builtin_amdgcn_s_setprio(0);
    BAR();

    // ---- P4: stage B1(kt+2); counted vmcnt; Q(1,0) (b0 retained in regs)
    if (kt + 2 < NKT) {
      stB(o2.b, o2.ldb, o2.k0, bcol, wB2, 1, tid);
      VMCNT6();
    } else if (kt + 1 < NKT) {
      VMCNT0();
    }
    BAR();
    __builtin_amdgcn_s_setprio(1);
#pragma unroll
    for (int m = 0; m < 4; ++m)
#pragma unroll
      for (int n = 0; n < 2; ++n)
#pragma unroll
        for (int ks = 0; ks < 2; ++ks)
          acc[1][0][m][n] = __builtin_amdgcn_mfma_f32_16x16x32_bf16(
              a[m][ks], b0[n][ks], acc[1][0][m][n], 0, 0, 0);
    __builtin_amdgcn_s_setprio(0);
    BAR();
  }

  // Epilogue: bias + f32 store (C/D: col=lane&15, row=(lane>>4)*4+j)
  int rg = lane >> 4;
#pragma unroll
  for (int mh = 0; mh < 2; ++mh)
#pragma unroll
    for (int nh = 0; nh < 2; ++nh)
#pragma unroll
      for (int n = 0; n < 2; ++n) {
        long col = bcol + wc*64 + nh*32 + n*16 + r16;
        float bv = bias[col];
#pragma unroll
        for (int m = 0; m < 4; ++m) {
          long row0 = brow + wr*128 + mh*64 + m*16 + rg*4;
#pragma unroll
          for (int j = 0; j < 4; ++j)
            out[(row0 + j)*4096 + col] = acc[mh][nh][m][n][j] + bv;
        }
      }
}

// ---------------------------------------------------------------------------
extern "C" void kernel_launch(void* const* d_in, const int* in_sizes, int n_in,
                              void* d_out, int out_size, void* d_ws, size_t ws_size,
                              hipStream_t stream) {
  (void)in_sizes; (void)n_in; (void)out_size; (void)ws_size;
  const float* x  = (const float*)d_in[0];
  const float* Wb = (const float*)d_in[1];
  const float* bb = (const float*)d_in[2];
  const float* Wg = (const float*)d_in[3];
  const float* A  = (const float*)d_in[4];
  const float* B  = (const float*)d_in[5];
  float* out = (float*)d_out;
  char* ws = (char*)d_ws;

  unsigned short* Xbf = (unsigned short*)(ws + WS_XBF);
  unsigned short* Wbf = (unsigned short*)(ws + WS_WBF);
  unsigned short* AG  = (unsigned short*)(ws + WS_AG);
  unsigned short* U   = (unsigned short*)(ws + WS_U);
  unsigned short* HW  = (unsigned short*)(ws + WS_HW);
  unsigned short* HP  = (unsigned short*)(ws + WS_HP);

  hipLaunchKernelGGL(prep_kernel, dim3(2048), dim3(256), 0, stream,
                     x, Wb, Wg, A, B, Xbf, Wbf, AG, U);
  hipLaunchKernelGGL(gate_partial, dim3(512), dim3(256), 0, stream,
                     Xbf, AG, HP);
  hipLaunchKernelGGL(gate_reduce, dim3(128), dim3(256), 0, stream,
                     HP, HW);
  hipLaunchKernelGGL(gemm8, dim3(512), dim3(512), 0, stream,
                     Xbf, Wbf, HW, U, bb, out);
}